// Round 2
// baseline (434.514 us; speedup 1.0000x reference)
//
#include <hip/hip_runtime.h>
#include <hip/hip_bf16.h>

#define N 8192
#define THREADS 256
#define S_CHUNKS 16
#define JCHUNK (N / S_CHUNKS)   // 512
#define TJ 256

// ---- workspace byte offsets (total ~2.67 MB) ----
#define POS_OFF   0u            // float4[N]            131072 B
#define Y1_OFF    131072u       // float[N*32]         1048576 B
#define Y1S_OFF   1179648u      // float[N*32] atomic  1048576 B
#define CNT_OFF   2228224u      // float[N]   atomic     32768 B
#define Y2_OFF    2260992u      // float[N*8]           262144 B
#define Y2S_OFF   2523136u      // float[N*8] atomic    262144 B
#define PAR_OFF   2785280u      // float[1728]            6912 B
#define FLAG_OFF  2792192u      // int                       4 B

// params layout (float offsets within PAR)
#define P_B    0      // 48
#define P_EMB  48     // 104
#define P_W1   152    // 1280
#define P_B1   1432   // 32
#define P_W2   1464   // 256
#define P_B2   1720   // 8

__device__ __forceinline__ float bf2f(__hip_bfloat16 x) { return __bfloat162float(x); }

// ---------------- detect input dtype + canonicalize params to fp32 ----------------
__global__ __launch_bounds__(256) void k_detect(
    const void* __restrict__ lpf, const void* __restrict__ B,
    const void* __restrict__ emb, const void* __restrict__ W1,
    const void* __restrict__ b1,  const void* __restrict__ W2,
    const void* __restrict__ b2,  char* __restrict__ ws)
{
    __shared__ int sbad;
    const int tid = threadIdx.x;
    if (tid == 0) sbad = 0;
    __syncthreads();
    const __hip_bfloat16* lb = (const __hip_bfloat16*)lpf;
    int bad = 0;
    for (int i = tid; i < 2048; i += 256) {
        const float v = bf2f(lb[i]);
        if (!(fabsf(v) <= 100.0f)) bad = 1;   // catches NaN and huge values
    }
    if (bad) atomicOr(&sbad, 1);
    __syncthreads();
    const int flag = sbad;   // 1 => inputs are float32, 0 => bf16

    float* par = (float*)(ws + PAR_OFF);
    const void* srcs[6] = { B, emb, W1, b1, W2, b2 };
    const int offs[6]   = { P_B, P_EMB, P_W1, P_B1, P_W2, P_B2 };
    const int cnts[6]   = { 48, 104, 1280, 32, 256, 8 };
    for (int a = 0; a < 6; ++a) {
        if (flag) {
            const float* s = (const float*)srcs[a];
            for (int i = tid; i < cnts[a]; i += 256) par[offs[a] + i] = s[i];
        } else {
            const __hip_bfloat16* s = (const __hip_bfloat16*)srcs[a];
            for (int i = tid; i < cnts[a]; i += 256) par[offs[a] + i] = bf2f(s[i]);
        }
    }
    if (tid == 0) *(int*)(ws + FLAG_OFF) = flag;
}

// ---------------- zero the atomic accumulators (ws is poisoned 0xAA each call) ----------------
__global__ __launch_bounds__(256) void k_zero(char* __restrict__ ws)
{
    float* p = (float*)(ws + Y1S_OFF);
    const int total = (int)((PAR_OFF - Y1S_OFF) / 4);   // zero y1s,cnt,y2,y2s
    for (int i = blockIdx.x * blockDim.x + threadIdx.x; i < total; i += gridDim.x * blockDim.x)
        p[i] = 0.0f;
}

// ---------------- prep: features + y1 = x@W1+b1 ----------------
__global__ __launch_bounds__(256) void k_prep(
    const void* __restrict__ lpf, char* __restrict__ ws)
{
    __shared__ float sB[48], sEmb[104], sW1[1280], sb1[32];
    const float* par = (const float*)(ws + PAR_OFF);
    const int tid = threadIdx.x;
    for (int i = tid; i < 48;   i += THREADS) sB[i]   = par[P_B + i];
    for (int i = tid; i < 104;  i += THREADS) sEmb[i] = par[P_EMB + i];
    for (int i = tid; i < 1280; i += THREADS) sW1[i]  = par[P_W1 + i];
    for (int i = tid; i < 32;   i += THREADS) sb1[i]  = par[P_B1 + i];
    __syncthreads();

    const int flag = *(const int*)(ws + FLAG_OFF);
    const int row = blockIdx.x * THREADS + tid;
    float px, py, pz, fraw;
    if (flag) {
        const float* lp = (const float*)lpf + (size_t)row * 4;
        px = lp[0]; py = lp[1]; pz = lp[2]; fraw = lp[3];
    } else {
        const __hip_bfloat16* lp = (const __hip_bfloat16*)lpf + (size_t)row * 4;
        px = bf2f(lp[0]); py = bf2f(lp[1]); pz = bf2f(lp[2]); fraw = bf2f(lp[3]);
    }
    int fi = (int)fraw;
    fi = fi < 0 ? 0 : (fi > 12 ? 12 : fi);
    ((float4*)(ws + POS_OFF))[row] = make_float4(px, py, pz, 0.0f);

    const float TWO_PI = 6.283185307179586f;
    float xf[40];
    #pragma unroll
    for (int k = 0; k < 16; ++k) {
        const float pr = (px * sB[k] + py * sB[16 + k] + pz * sB[32 + k]) * TWO_PI;
        xf[k]      = sinf(pr);
        xf[16 + k] = cosf(pr);
    }
    #pragma unroll
    for (int m = 0; m < 8; ++m) xf[32 + m] = sEmb[fi * 8 + m];

    float acc[32];
    #pragma unroll
    for (int c = 0; c < 32; ++c) acc[c] = sb1[c];
    #pragma unroll
    for (int f = 0; f < 40; ++f) {
        const float xv = xf[f];
        #pragma unroll
        for (int c = 0; c < 32; ++c) acc[c] += xv * sW1[f * 32 + c];
    }
    float4* y4 = (float4*)((float*)(ws + Y1_OFF) + (size_t)row * 32);
    #pragma unroll
    for (int k = 0; k < 8; ++k)
        y4[k] = make_float4(acc[4*k], acc[4*k+1], acc[4*k+2], acc[4*k+3]);
}

// ---------------- agg1: masked sums of y1 (+count) via atomics ----------------
__global__ __launch_bounds__(256) void k_agg1(char* __restrict__ ws)
{
    __shared__ float4 sp[TJ];
    __shared__ float  sy[TJ * 32];

    const float4* pos4 = (const float4*)(ws + POS_OFF);
    const float*  y1   = (const float*)(ws + Y1_OFF);
    float* y1s = (float*)(ws + Y1S_OFF);
    float* cnt = (float*)(ws + CNT_OFF);

    const int tid = threadIdx.x;
    const int row = blockIdx.x * THREADS + tid;
    const int j0  = blockIdx.y * JCHUNK;

    const float4 p = pos4[row];
    float acc[32];
    #pragma unroll
    for (int c = 0; c < 32; ++c) acc[c] = 0.0f;
    float c_loc = 0.0f;

    for (int t = 0; t < JCHUNK / TJ; ++t) {
        const int jb = j0 + t * TJ;
        __syncthreads();
        sp[tid] = pos4[jb + tid];
        float4* sy4 = (float4*)sy;
        const float4* g4 = (const float4*)(y1 + (size_t)jb * 32);
        #pragma unroll
        for (int k = 0; k < 8; ++k)
            sy4[tid + k * THREADS] = g4[tid + k * THREADS];
        __syncthreads();

        #pragma unroll 2
        for (int jj = 0; jj < TJ; ++jj) {
            const float4 q = sp[jj];
            const float dx = p.x - q.x, dy = p.y - q.y, dz = p.z - q.z;
            const float d2 = dx*dx + dy*dy + dz*dz;
            const float m = (d2 < 6.25f) ? 1.0f : 0.0f;
            c_loc += m;
            const float4* yv = (const float4*)(sy + jj * 32);
            #pragma unroll
            for (int k = 0; k < 8; ++k) {
                const float4 v = yv[k];
                acc[4*k+0] += m * v.x;
                acc[4*k+1] += m * v.y;
                acc[4*k+2] += m * v.z;
                acc[4*k+3] += m * v.w;
            }
        }
    }

    float* dst = y1s + (size_t)row * 32;
    #pragma unroll
    for (int c = 0; c < 32; ++c) atomicAdd(dst + c, acc[c]);
    atomicAdd(cnt + row, c_loc);
}

// ---------------- mlp2: h = relu(mean); y2 = h@W2+b2 ----------------
__global__ __launch_bounds__(256) void k_mlp2(char* __restrict__ ws)
{
    __shared__ float sW2[256], sb2[8];
    const float* par = (const float*)(ws + PAR_OFF);
    const int tid = threadIdx.x;
    for (int i = tid; i < 256; i += THREADS) sW2[i] = par[P_W2 + i];
    if (tid < 8) sb2[tid] = par[P_B2 + tid];
    __syncthreads();

    const int row = blockIdx.x * THREADS + tid;
    const float* y1s = (const float*)(ws + Y1S_OFF);
    const float  cnt = ((const float*)(ws + CNT_OFF))[row];
    const float  inv = 1.0f / (cnt + 1e-6f);

    float o[8];
    #pragma unroll
    for (int j = 0; j < 8; ++j) o[j] = sb2[j];
    const float4* s4 = (const float4*)(y1s + (size_t)row * 32);
    #pragma unroll
    for (int k = 0; k < 8; ++k) {
        const float4 v = s4[k];
        const float h0 = fmaxf(v.x * inv, 0.0f);
        const float h1 = fmaxf(v.y * inv, 0.0f);
        const float h2 = fmaxf(v.z * inv, 0.0f);
        const float h3 = fmaxf(v.w * inv, 0.0f);
        #pragma unroll
        for (int j = 0; j < 8; ++j)
            o[j] += h0 * sW2[(4*k+0)*8+j] + h1 * sW2[(4*k+1)*8+j]
                  + h2 * sW2[(4*k+2)*8+j] + h3 * sW2[(4*k+3)*8+j];
    }
    float4* y4 = (float4*)((float*)(ws + Y2_OFF) + (size_t)row * 8);
    y4[0] = make_float4(o[0], o[1], o[2], o[3]);
    y4[1] = make_float4(o[4], o[5], o[6], o[7]);
}

// ---------------- agg2: masked sums of y2 via atomics ----------------
__global__ __launch_bounds__(256) void k_agg2(char* __restrict__ ws)
{
    __shared__ float4 sp[TJ];
    __shared__ float  sy[TJ * 8];

    const float4* pos4 = (const float4*)(ws + POS_OFF);
    const float*  y2   = (const float*)(ws + Y2_OFF);
    float* y2s = (float*)(ws + Y2S_OFF);

    const int tid = threadIdx.x;
    const int row = blockIdx.x * THREADS + tid;
    const int j0  = blockIdx.y * JCHUNK;

    const float4 p = pos4[row];
    float acc[8];
    #pragma unroll
    for (int c = 0; c < 8; ++c) acc[c] = 0.0f;

    for (int t = 0; t < JCHUNK / TJ; ++t) {
        const int jb = j0 + t * TJ;
        __syncthreads();
        sp[tid] = pos4[jb + tid];
        float4* sy4 = (float4*)sy;
        const float4* g4 = (const float4*)(y2 + (size_t)jb * 8);
        #pragma unroll
        for (int k = 0; k < 2; ++k)
            sy4[tid + k * THREADS] = g4[tid + k * THREADS];
        __syncthreads();

        #pragma unroll 2
        for (int jj = 0; jj < TJ; ++jj) {
            const float4 q = sp[jj];
            const float dx = p.x - q.x, dy = p.y - q.y, dz = p.z - q.z;
            const float d2 = dx*dx + dy*dy + dz*dz;
            const float m = (d2 < 6.25f) ? 1.0f : 0.0f;
            const float4* yv = (const float4*)(sy + jj * 8);
            const float4 v0 = yv[0], v1 = yv[1];
            acc[0] += m * v0.x; acc[1] += m * v0.y; acc[2] += m * v0.z; acc[3] += m * v0.w;
            acc[4] += m * v1.x; acc[5] += m * v1.y; acc[6] += m * v1.z; acc[7] += m * v1.w;
        }
    }

    float* dst = y2s + (size_t)row * 8;
    #pragma unroll
    for (int c = 0; c < 8; ++c) atomicAdd(dst + c, acc[c]);
}

// ---------------- out = relu(mean) in detected dtype ----------------
__global__ __launch_bounds__(256) void k_out(char* __restrict__ ws, void* __restrict__ out)
{
    const int tid = threadIdx.x;
    const int row = blockIdx.x * THREADS + tid;
    const int flag = *(const int*)(ws + FLAG_OFF);
    const float* y2s = (const float*)(ws + Y2S_OFF);
    const float  cnt = ((const float*)(ws + CNT_OFF))[row];
    const float  inv = 1.0f / (cnt + 1e-6f);
    const float* s = y2s + (size_t)row * 8;
    if (flag) {
        float* op = (float*)out + (size_t)row * 8;
        #pragma unroll
        for (int c = 0; c < 8; ++c) op[c] = fmaxf(s[c] * inv, 0.0f);
    } else {
        __hip_bfloat16* op = (__hip_bfloat16*)out + (size_t)row * 8;
        #pragma unroll
        for (int c = 0; c < 8; ++c) op[c] = __float2bfloat16(fmaxf(s[c] * inv, 0.0f));
    }
}

extern "C" void kernel_launch(void* const* d_in, const int* in_sizes, int n_in,
                              void* d_out, int out_size, void* d_ws, size_t ws_size,
                              hipStream_t stream) {
    (void)in_sizes; (void)n_in; (void)out_size; (void)ws_size;
    char* ws = (char*)d_ws;
    k_detect<<<1, THREADS, 0, stream>>>(d_in[0], d_in[1], d_in[2], d_in[3], d_in[4], d_in[5], d_in[6], ws);
    k_zero  <<<64, THREADS, 0, stream>>>(ws);
    k_prep  <<<N / THREADS, THREADS, 0, stream>>>(d_in[0], ws);
    k_agg1  <<<dim3(N / THREADS, S_CHUNKS), THREADS, 0, stream>>>(ws);
    k_mlp2  <<<N / THREADS, THREADS, 0, stream>>>(ws);
    k_agg2  <<<dim3(N / THREADS, S_CHUNKS), THREADS, 0, stream>>>(ws);
    k_out   <<<N / THREADS, THREADS, 0, stream>>>(ws, d_out);
}

// Round 3
// 142.532 us; speedup vs baseline: 3.0485x; 3.0485x over previous
//
#include <hip/hip_runtime.h>
#include <hip/hip_bf16.h>

#define N 8192
#define THREADS 256
#define KCHUNKS 4
#define KCHUNK (N / KCHUNKS)   // 2048
#define BK 256
#define YSTR 264               // padded LDS stride (elements)
#define PSTR 264

typedef __attribute__((ext_vector_type(8))) short short8;
typedef __attribute__((ext_vector_type(4))) float floatx4;

// ---- workspace byte offsets (total ~2.89 MB) ----
#define POS4_OFF  0u          // float4[N]        131072
#define POST_OFF  131072u     // float[3*N]        98304
#define Y1T_OFF   229376u     // bf16[64*N]      1048576
#define Y2T_OFF   1277952u    // bf16[16*N]       262144
#define Y1S_OFF   1540096u    // float[N*32]     1048576  (atomic)
#define CNT_OFF   2588672u    // float[N]          32768  (atomic)
#define Y2S_OFF   2621440u    // float[N*8]       262144  (atomic)
#define PAR_OFF   2883584u    // float[1728]        6912
#define FLAG_OFF  2890496u    // int

#define P_B    0
#define P_EMB  48
#define P_W1   152
#define P_B1   1432
#define P_W2   1464
#define P_B2   1720

__device__ __forceinline__ float bf2f(__hip_bfloat16 x) { return __bfloat162float(x); }

// ---------------- detect input dtype + canonicalize params to fp32 ----------------
__global__ __launch_bounds__(256) void k_detect(
    const void* __restrict__ lpf, const void* __restrict__ B,
    const void* __restrict__ emb, const void* __restrict__ W1,
    const void* __restrict__ b1,  const void* __restrict__ W2,
    const void* __restrict__ b2,  char* __restrict__ ws)
{
    __shared__ int sbad;
    const int tid = threadIdx.x;
    if (tid == 0) sbad = 0;
    __syncthreads();
    const __hip_bfloat16* lb = (const __hip_bfloat16*)lpf;
    int bad = 0;
    for (int i = tid; i < 2048; i += 256) {
        const float v = bf2f(lb[i]);
        if (!(fabsf(v) <= 100.0f)) bad = 1;
    }
    if (bad) atomicOr(&sbad, 1);
    __syncthreads();
    const int flag = sbad;   // 1 => float32 inputs, 0 => bf16

    float* par = (float*)(ws + PAR_OFF);
    const void* srcs[6] = { B, emb, W1, b1, W2, b2 };
    const int offs[6]   = { P_B, P_EMB, P_W1, P_B1, P_W2, P_B2 };
    const int cnts[6]   = { 48, 104, 1280, 32, 256, 8 };
    for (int a = 0; a < 6; ++a) {
        if (flag) {
            const float* s = (const float*)srcs[a];
            for (int i = tid; i < cnts[a]; i += 256) par[offs[a] + i] = s[i];
        } else {
            const __hip_bfloat16* s = (const __hip_bfloat16*)srcs[a];
            for (int i = tid; i < cnts[a]; i += 256) par[offs[a] + i] = bf2f(s[i]);
        }
    }
    if (tid == 0) *(int*)(ws + FLAG_OFF) = flag;
}

// ---------------- zero atomic accumulators (y1s, cnt, y2s contiguous) ----------------
__global__ __launch_bounds__(256) void k_zero(char* __restrict__ ws)
{
    float* p = (float*)(ws + Y1S_OFF);
    const int total = (int)((PAR_OFF - Y1S_OFF) / 4);
    for (int i = blockIdx.x * blockDim.x + threadIdx.x; i < total; i += gridDim.x * blockDim.x)
        p[i] = 0.0f;
}

// ---------------- prep: pos4/posT + y1 = x@W1+b1 -> y1T hi/lo bf16 [64][N] ----------------
__global__ __launch_bounds__(256) void k_prep(
    const void* __restrict__ lpf, char* __restrict__ ws)
{
    __shared__ float sB[48], sEmb[104], sW1[1280], sb1[32];
    __shared__ __hip_bfloat16 sT[64 * YSTR];
    const float* par = (const float*)(ws + PAR_OFF);
    const int tid = threadIdx.x;
    for (int i = tid; i < 48;   i += THREADS) sB[i]   = par[P_B + i];
    for (int i = tid; i < 104;  i += THREADS) sEmb[i] = par[P_EMB + i];
    for (int i = tid; i < 1280; i += THREADS) sW1[i]  = par[P_W1 + i];
    for (int i = tid; i < 32;   i += THREADS) sb1[i]  = par[P_B1 + i];
    __syncthreads();

    const int flag = *(const int*)(ws + FLAG_OFF);
    const int row = blockIdx.x * THREADS + tid;
    float px, py, pz, fraw;
    if (flag) {
        const float* lp = (const float*)lpf + (size_t)row * 4;
        px = lp[0]; py = lp[1]; pz = lp[2]; fraw = lp[3];
    } else {
        const __hip_bfloat16* lp = (const __hip_bfloat16*)lpf + (size_t)row * 4;
        px = bf2f(lp[0]); py = bf2f(lp[1]); pz = bf2f(lp[2]); fraw = bf2f(lp[3]);
    }
    int fi = (int)fraw;
    fi = fi < 0 ? 0 : (fi > 12 ? 12 : fi);
    ((float4*)(ws + POS4_OFF))[row] = make_float4(px, py, pz, 0.0f);
    float* posT = (float*)(ws + POST_OFF);
    posT[row] = px; posT[N + row] = py; posT[2 * N + row] = pz;

    const float TWO_PI = 6.283185307179586f;
    float xf[40];
    #pragma unroll
    for (int k = 0; k < 16; ++k) {
        const float pr = (px * sB[k] + py * sB[16 + k] + pz * sB[32 + k]) * TWO_PI;
        xf[k]      = sinf(pr);
        xf[16 + k] = cosf(pr);
    }
    #pragma unroll
    for (int m = 0; m < 8; ++m) xf[32 + m] = sEmb[fi * 8 + m];

    float acc[32];
    #pragma unroll
    for (int c = 0; c < 32; ++c) acc[c] = sb1[c];
    #pragma unroll
    for (int f = 0; f < 40; ++f) {
        const float xv = xf[f];
        #pragma unroll
        for (int c = 0; c < 32; ++c) acc[c] += xv * sW1[f * 32 + c];
    }
    // hi/lo split into LDS transpose tile: rows 0-31 hi, 32-63 lo; col = tid
    #pragma unroll
    for (int c = 0; c < 32; ++c) {
        const __hip_bfloat16 h = __float2bfloat16(acc[c]);
        const __hip_bfloat16 l = __float2bfloat16(acc[c] - bf2f(h));
        sT[c * YSTR + tid]        = h;
        sT[(32 + c) * YSTR + tid] = l;
    }
    __syncthreads();
    // coalesced write y1T[64][N] slice cols [blk*256, +256)
    __hip_bfloat16* y1t = (__hip_bfloat16*)(ws + Y1T_OFF);
    const int kb = blockIdx.x * THREADS;
    const int c32 = tid & 31, r8 = tid >> 5;
    #pragma unroll
    for (int rr = 0; rr < 8; ++rr) {
        const int r = r8 + rr * 8;
        *(uint4*)(y1t + (size_t)r * N + kb + c32 * 8) = *(const uint4*)&sT[r * YSTR + c32 * 8];
    }
}

// ---------------- agg1: sums(A @ [y1_hi|y1_lo]) + cnt via MFMA ----------------
__global__ __launch_bounds__(256) void k_agg1(char* __restrict__ ws)
{
    __shared__ __hip_bfloat16 sY[64 * YSTR];
    __shared__ float sPos[3 * PSTR];

    const float4* pos4 = (const float4*)(ws + POS4_OFF);
    const float* posT  = (const float*)(ws + POST_OFF);
    const __hip_bfloat16* y1t = (const __hip_bfloat16*)(ws + Y1T_OFF);
    float* y1s = (float*)(ws + Y1S_OFF);
    float* cnt = (float*)(ws + CNT_OFF);

    const int tid  = threadIdx.x;
    const int lane = tid & 63;
    const int wv   = tid >> 6;        // wave 0..3
    const int quad = lane >> 4;       // 0..3
    const int ncol = lane & 15;
    const int rowbase = blockIdx.x * 64;
    const int kcbase  = blockIdx.y * KCHUNK;

    // A-side row position for this lane (m = ncol)
    const float4 pr = pos4[rowbase + wv * 16 + ncol];
    const float prx = pr.x, pry = pr.y, prz = pr.z;

    short8 bones;
    #pragma unroll
    for (int j = 0; j < 8; ++j) bones[j] = (ncol == 0) ? (short)0x3F80 : (short)0;

    floatx4 acc0 = {0.f,0.f,0.f,0.f}, acc1 = {0.f,0.f,0.f,0.f};
    floatx4 acc2 = {0.f,0.f,0.f,0.f}, acc3 = {0.f,0.f,0.f,0.f};
    floatx4 accc = {0.f,0.f,0.f,0.f};

    const int c32 = tid & 31, r8 = tid >> 5;
    for (int kb = kcbase; kb < kcbase + KCHUNK; kb += BK) {
        __syncthreads();
        // stage y1T slice [64][BK] and posT slice [3][BK]
        #pragma unroll
        for (int rr = 0; rr < 8; ++rr) {
            const int r = r8 + rr * 8;
            *(uint4*)&sY[r * YSTR + c32 * 8] = *(const uint4*)(y1t + (size_t)r * N + kb + c32 * 8);
        }
        if (tid < 192) {
            const int dim = tid >> 6, i = tid & 63;
            *(float4*)&sPos[dim * PSTR + i * 4] = *(const float4*)(posT + (size_t)dim * N + kb + i * 4);
        }
        __syncthreads();

        for (int kt = 0; kt < BK; kt += 32) {
            const int koff = kt + quad * 8;
            const float4 xa = *(const float4*)&sPos[koff];
            const float4 xb = *(const float4*)&sPos[koff + 4];
            const float4 ya = *(const float4*)&sPos[PSTR + koff];
            const float4 yb = *(const float4*)&sPos[PSTR + koff + 4];
            const float4 za = *(const float4*)&sPos[2 * PSTR + koff];
            const float4 zb = *(const float4*)&sPos[2 * PSTR + koff + 4];

            short8 af;
            #define MK(PX,PY,PZ,IDX) { const float dx = prx-(PX), dy = pry-(PY), dz = prz-(PZ); \
                const float d2 = dx*dx + dy*dy + dz*dz; af[IDX] = (d2 < 6.25f) ? (short)0x3F80 : (short)0; }
            MK(xa.x, ya.x, za.x, 0) MK(xa.y, ya.y, za.y, 1) MK(xa.z, ya.z, za.z, 2) MK(xa.w, ya.w, za.w, 3)
            MK(xb.x, yb.x, zb.x, 4) MK(xb.y, yb.y, zb.y, 5) MK(xb.z, yb.z, zb.z, 6) MK(xb.w, yb.w, zb.w, 7)
            #undef MK

            const short8 b0 = *(const short8*)&sY[(ncol)      * YSTR + koff];
            const short8 b1 = *(const short8*)&sY[(16 + ncol) * YSTR + koff];
            const short8 b2 = *(const short8*)&sY[(32 + ncol) * YSTR + koff];
            const short8 b3 = *(const short8*)&sY[(48 + ncol) * YSTR + koff];

            acc0 = __builtin_amdgcn_mfma_f32_16x16x32_bf16(af, b0, acc0, 0, 0, 0);
            acc1 = __builtin_amdgcn_mfma_f32_16x16x32_bf16(af, b1, acc1, 0, 0, 0);
            acc2 = __builtin_amdgcn_mfma_f32_16x16x32_bf16(af, b2, acc2, 0, 0, 0);
            acc3 = __builtin_amdgcn_mfma_f32_16x16x32_bf16(af, b3, acc3, 0, 0, 0);
            accc = __builtin_amdgcn_mfma_f32_16x16x32_bf16(af, bones, accc, 0, 0, 0);
        }
    }

    // C layout: col = ncol, row = quad*4 + r  (verified m89/m91)
    const int orow0 = rowbase + wv * 16 + quad * 4;
    #pragma unroll
    for (int r = 0; r < 4; ++r) {
        const int orow = orow0 + r;
        atomicAdd(&y1s[(size_t)orow * 32 + ncol],      acc0[r] + acc2[r]);
        atomicAdd(&y1s[(size_t)orow * 32 + 16 + ncol], acc1[r] + acc3[r]);
        if (ncol == 0) atomicAdd(&cnt[orow], accc[r]);
    }
}

// ---------------- mlp2: h = relu(sum/(cnt+eps)); y2 = h@W2+b2 -> y2T hi/lo [16][N] ----------------
__global__ __launch_bounds__(256) void k_mlp2(char* __restrict__ ws)
{
    __shared__ float sW2[256], sb2[8];
    __shared__ __hip_bfloat16 sT[16 * YSTR];
    const float* par = (const float*)(ws + PAR_OFF);
    const int tid = threadIdx.x;
    for (int i = tid; i < 256; i += THREADS) sW2[i] = par[P_W2 + i];
    if (tid < 8) sb2[tid] = par[P_B2 + tid];
    __syncthreads();

    const int row = blockIdx.x * THREADS + tid;
    const float* y1s = (const float*)(ws + Y1S_OFF);
    const float  cv  = ((const float*)(ws + CNT_OFF))[row];
    const float  inv = 1.0f / (cv + 1e-6f);

    float o[8];
    #pragma unroll
    for (int j = 0; j < 8; ++j) o[j] = sb2[j];
    const float4* s4 = (const float4*)(y1s + (size_t)row * 32);
    #pragma unroll
    for (int k = 0; k < 8; ++k) {
        const float4 v = s4[k];
        const float h0 = fmaxf(v.x * inv, 0.0f);
        const float h1 = fmaxf(v.y * inv, 0.0f);
        const float h2 = fmaxf(v.z * inv, 0.0f);
        const float h3 = fmaxf(v.w * inv, 0.0f);
        #pragma unroll
        for (int j = 0; j < 8; ++j)
            o[j] += h0 * sW2[(4*k+0)*8+j] + h1 * sW2[(4*k+1)*8+j]
                  + h2 * sW2[(4*k+2)*8+j] + h3 * sW2[(4*k+3)*8+j];
    }
    #pragma unroll
    for (int j = 0; j < 8; ++j) {
        const __hip_bfloat16 h = __float2bfloat16(o[j]);
        const __hip_bfloat16 l = __float2bfloat16(o[j] - bf2f(h));
        sT[j * YSTR + tid]       = h;
        sT[(8 + j) * YSTR + tid] = l;
    }
    __syncthreads();
    __hip_bfloat16* y2t = (__hip_bfloat16*)(ws + Y2T_OFF);
    const int kb = blockIdx.x * THREADS;
    const int c32 = tid & 31, r8 = tid >> 5;
    #pragma unroll
    for (int rr = 0; rr < 2; ++rr) {
        const int r = r8 + rr * 8;
        *(uint4*)(y2t + (size_t)r * N + kb + c32 * 8) = *(const uint4*)&sT[r * YSTR + c32 * 8];
    }
}

// ---------------- agg2: sums(A @ [y2_hi|y2_lo]) via MFMA (cnt reused) ----------------
__global__ __launch_bounds__(256) void k_agg2(char* __restrict__ ws)
{
    __shared__ __hip_bfloat16 sY[16 * YSTR];
    __shared__ float sPos[3 * PSTR];

    const float4* pos4 = (const float4*)(ws + POS4_OFF);
    const float* posT  = (const float*)(ws + POST_OFF);
    const __hip_bfloat16* y2t = (const __hip_bfloat16*)(ws + Y2T_OFF);
    float* y2s = (float*)(ws + Y2S_OFF);

    const int tid  = threadIdx.x;
    const int lane = tid & 63;
    const int wv   = tid >> 6;
    const int quad = lane >> 4;
    const int ncol = lane & 15;
    const int rowbase = blockIdx.x * 64;
    const int kcbase  = blockIdx.y * KCHUNK;

    const float4 pr = pos4[rowbase + wv * 16 + ncol];
    const float prx = pr.x, pry = pr.y, prz = pr.z;

    floatx4 acc = {0.f,0.f,0.f,0.f};

    const int c32 = tid & 31, r8 = tid >> 5;
    for (int kb = kcbase; kb < kcbase + KCHUNK; kb += BK) {
        __syncthreads();
        {   // stage y2T slice [16][BK]: 16*256*2B = 8KB -> 512 uint4, 2 per thread
            #pragma unroll
            for (int rr = 0; rr < 2; ++rr) {
                const int r = r8 + rr * 8;
                *(uint4*)&sY[r * YSTR + c32 * 8] = *(const uint4*)(y2t + (size_t)r * N + kb + c32 * 8);
            }
            if (tid < 192) {
                const int dim = tid >> 6, i = tid & 63;
                *(float4*)&sPos[dim * PSTR + i * 4] = *(const float4*)(posT + (size_t)dim * N + kb + i * 4);
            }
        }
        __syncthreads();

        for (int kt = 0; kt < BK; kt += 32) {
            const int koff = kt + quad * 8;
            const float4 xa = *(const float4*)&sPos[koff];
            const float4 xb = *(const float4*)&sPos[koff + 4];
            const float4 ya = *(const float4*)&sPos[PSTR + koff];
            const float4 yb = *(const float4*)&sPos[PSTR + koff + 4];
            const float4 za = *(const float4*)&sPos[2 * PSTR + koff];
            const float4 zb = *(const float4*)&sPos[2 * PSTR + koff + 4];

            short8 af;
            #define MK(PX,PY,PZ,IDX) { const float dx = prx-(PX), dy = pry-(PY), dz = prz-(PZ); \
                const float d2 = dx*dx + dy*dy + dz*dz; af[IDX] = (d2 < 6.25f) ? (short)0x3F80 : (short)0; }
            MK(xa.x, ya.x, za.x, 0) MK(xa.y, ya.y, za.y, 1) MK(xa.z, ya.z, za.z, 2) MK(xa.w, ya.w, za.w, 3)
            MK(xb.x, yb.x, zb.x, 4) MK(xb.y, yb.y, zb.y, 5) MK(xb.z, yb.z, zb.z, 6) MK(xb.w, yb.w, zb.w, 7)
            #undef MK

            const short8 b0 = *(const short8*)&sY[ncol * YSTR + koff];
            acc = __builtin_amdgcn_mfma_f32_16x16x32_bf16(af, b0, acc, 0, 0, 0);
        }
    }

    // cols 0-7 = hi sums, 8-15 = lo sums -> combine via shfl_xor(8)
    const int orow0 = rowbase + wv * 16 + quad * 4;
    #pragma unroll
    for (int r = 0; r < 4; ++r) {
        const float partner = __shfl_xor(acc[r], 8);
        if (ncol < 8) {
            const int orow = orow0 + r;
            atomicAdd(&y2s[(size_t)orow * 8 + ncol], acc[r] + partner);
        }
    }
}

// ---------------- out = relu(sum/(cnt+eps)) in detected dtype ----------------
__global__ __launch_bounds__(256) void k_out(char* __restrict__ ws, void* __restrict__ out)
{
    const int tid = threadIdx.x;
    const int row = blockIdx.x * THREADS + tid;
    const int flag = *(const int*)(ws + FLAG_OFF);
    const float* y2s = (const float*)(ws + Y2S_OFF);
    const float  cv  = ((const float*)(ws + CNT_OFF))[row];
    const float  inv = 1.0f / (cv + 1e-6f);
    const float* s = y2s + (size_t)row * 8;
    if (flag) {
        float* op = (float*)out + (size_t)row * 8;
        #pragma unroll
        for (int c = 0; c < 8; ++c) op[c] = fmaxf(s[c] * inv, 0.0f);
    } else {
        __hip_bfloat16* op = (__hip_bfloat16*)out + (size_t)row * 8;
        #pragma unroll
        for (int c = 0; c < 8; ++c) op[c] = __float2bfloat16(fmaxf(s[c] * inv, 0.0f));
    }
}

extern "C" void kernel_launch(void* const* d_in, const int* in_sizes, int n_in,
                              void* d_out, int out_size, void* d_ws, size_t ws_size,
                              hipStream_t stream) {
    (void)in_sizes; (void)n_in; (void)out_size; (void)ws_size;
    char* ws = (char*)d_ws;
    k_detect<<<1, THREADS, 0, stream>>>(d_in[0], d_in[1], d_in[2], d_in[3], d_in[4], d_in[5], d_in[6], ws);
    k_zero  <<<64, THREADS, 0, stream>>>(ws);
    k_prep  <<<N / THREADS, THREADS, 0, stream>>>(d_in[0], ws);
    k_agg1  <<<dim3(N / 64, KCHUNKS), THREADS, 0, stream>>>(ws);
    k_mlp2  <<<N / THREADS, THREADS, 0, stream>>>(ws);
    k_agg2  <<<dim3(N / 64, KCHUNKS), THREADS, 0, stream>>>(ws);
    k_out   <<<N / THREADS, THREADS, 0, stream>>>(ws, d_out);
}

// Round 7
// 134.655 us; speedup vs baseline: 3.2269x; 1.0585x over previous
//
#include <hip/hip_runtime.h>
#include <hip/hip_bf16.h>

#define N 8192
#define THREADS 256
#define KCHUNKS 4
#define KCHUNK (N / KCHUNKS)   // 2048
#define BK 256
#define YSTR 264               // padded LDS stride (elements)
#define PSTR 264

typedef __attribute__((ext_vector_type(8))) short short8;
typedef __attribute__((ext_vector_type(4))) float floatx4;

// ---- workspace byte offsets (proven layout from round 3; ~2.89 MB) ----
#define POS4_OFF  0u          // float4[N]        131072
#define POST_OFF  131072u     // float[3*N]        98304
#define Y1T_OFF   229376u     // bf16[64*N]      1048576
#define Y2T_OFF   1277952u    // bf16[16*N]       262144
#define Y1S_OFF   1540096u    // float[N*32]     1048576  (atomic)
#define CNT_OFF   2588672u    // float[N]          32768  (atomic)
#define Y2S_OFF   2621440u    // float[N*8]       262144  (atomic)

__device__ __forceinline__ float bf2f(__hip_bfloat16 x) { return __bfloat162float(x); }

// ---------------- zero atomic accumulators (y1s, cnt, y2s contiguous) ----------------
__global__ __launch_bounds__(256) void k_zero(char* __restrict__ ws)
{
    float* p = (float*)(ws + Y1S_OFF);
    const int total = (int)((Y2S_OFF + 262144u - Y1S_OFF) / 4);
    for (int i = blockIdx.x * blockDim.x + threadIdx.x; i < total; i += gridDim.x * blockDim.x)
        p[i] = 0.0f;
}

// ---------------- prep: pos4/posT + y1 = x@W1+b1 -> y1T hi/lo bf16 [64][N] ----------------
__global__ __launch_bounds__(256) void k_prep(
    const float* __restrict__ lpf,    // (N,4) float32
    const float* __restrict__ Bm,     // (3,16)
    const float* __restrict__ emb,    // (13,8)
    const float* __restrict__ W1,     // (40,32)
    const float* __restrict__ b1,     // (32,)
    char* __restrict__ ws)
{
    __shared__ float sB[48], sEmb[104], sW1[1280], sb1[32];
    __shared__ __hip_bfloat16 sT[64 * YSTR];
    const int tid = threadIdx.x;
    for (int i = tid; i < 48;   i += THREADS) sB[i]   = Bm[i];
    for (int i = tid; i < 104;  i += THREADS) sEmb[i] = emb[i];
    for (int i = tid; i < 1280; i += THREADS) sW1[i]  = W1[i];
    for (int i = tid; i < 32;   i += THREADS) sb1[i]  = b1[i];
    __syncthreads();

    const int row = blockIdx.x * THREADS + tid;
    const float4 lp = ((const float4*)lpf)[row];
    const float px = lp.x, py = lp.y, pz = lp.z;
    int fi = (int)lp.w;
    fi = fi < 0 ? 0 : (fi > 12 ? 12 : fi);
    ((float4*)(ws + POS4_OFF))[row] = make_float4(px, py, pz, 0.0f);
    float* posT = (float*)(ws + POST_OFF);
    posT[row] = px; posT[N + row] = py; posT[2 * N + row] = pz;

    const float TWO_PI = 6.283185307179586f;
    float xf[40];
    #pragma unroll
    for (int k = 0; k < 16; ++k) {
        const float pr = (px * sB[k] + py * sB[16 + k] + pz * sB[32 + k]) * TWO_PI;
        xf[k]      = sinf(pr);
        xf[16 + k] = cosf(pr);
    }
    #pragma unroll
    for (int m = 0; m < 8; ++m) xf[32 + m] = sEmb[fi * 8 + m];

    float acc[32];
    #pragma unroll
    for (int c = 0; c < 32; ++c) acc[c] = sb1[c];
    #pragma unroll
    for (int f = 0; f < 40; ++f) {
        const float xv = xf[f];
        #pragma unroll
        for (int c = 0; c < 32; ++c) acc[c] += xv * sW1[f * 32 + c];
    }
    // hi/lo split into LDS transpose tile: rows 0-31 hi, 32-63 lo; col = tid
    #pragma unroll
    for (int c = 0; c < 32; ++c) {
        const __hip_bfloat16 h = __float2bfloat16(acc[c]);
        const __hip_bfloat16 l = __float2bfloat16(acc[c] - bf2f(h));
        sT[c * YSTR + tid]        = h;
        sT[(32 + c) * YSTR + tid] = l;
    }
    __syncthreads();
    __hip_bfloat16* y1t = (__hip_bfloat16*)(ws + Y1T_OFF);
    const int kb = blockIdx.x * THREADS;
    const int c32 = tid & 31, r8 = tid >> 5;
    #pragma unroll
    for (int rr = 0; rr < 8; ++rr) {
        const int r = r8 + rr * 8;
        *(uint4*)(y1t + (size_t)r * N + kb + c32 * 8) = *(const uint4*)&sT[r * YSTR + c32 * 8];
    }
}

// ---------------- agg1: sums(A @ [y1_hi|y1_lo]) + cnt via MFMA ----------------
__global__ __launch_bounds__(256) void k_agg1(char* __restrict__ ws)
{
    __shared__ __hip_bfloat16 sY[64 * YSTR];
    __shared__ float sPos[3 * PSTR];

    const float4* pos4 = (const float4*)(ws + POS4_OFF);
    const float* posT  = (const float*)(ws + POST_OFF);
    const __hip_bfloat16* y1t = (const __hip_bfloat16*)(ws + Y1T_OFF);
    float* y1s = (float*)(ws + Y1S_OFF);
    float* cnt = (float*)(ws + CNT_OFF);

    const int tid  = threadIdx.x;
    const int lane = tid & 63;
    const int wv   = tid >> 6;        // wave 0..3
    const int quad = lane >> 4;       // 0..3
    const int ncol = lane & 15;
    const int rowbase = blockIdx.x * 64;
    const int kcbase  = blockIdx.y * KCHUNK;

    const float4 pr = pos4[rowbase + wv * 16 + ncol];
    const float prx = pr.x, pry = pr.y, prz = pr.z;

    short8 bones;
    #pragma unroll
    for (int j = 0; j < 8; ++j) bones[j] = (ncol == 0) ? (short)0x3F80 : (short)0;

    floatx4 acc0 = {0.f,0.f,0.f,0.f}, acc1 = {0.f,0.f,0.f,0.f};
    floatx4 acc2 = {0.f,0.f,0.f,0.f}, acc3 = {0.f,0.f,0.f,0.f};
    floatx4 accc = {0.f,0.f,0.f,0.f};

    const int c32 = tid & 31, r8 = tid >> 5;
    for (int kb = kcbase; kb < kcbase + KCHUNK; kb += BK) {
        __syncthreads();
        #pragma unroll
        for (int rr = 0; rr < 8; ++rr) {
            const int r = r8 + rr * 8;
            *(uint4*)&sY[r * YSTR + c32 * 8] = *(const uint4*)(y1t + (size_t)r * N + kb + c32 * 8);
        }
        if (tid < 192) {
            const int dim = tid >> 6, i = tid & 63;
            *(float4*)&sPos[dim * PSTR + i * 4] = *(const float4*)(posT + (size_t)dim * N + kb + i * 4);
        }
        __syncthreads();

        for (int kt = 0; kt < BK; kt += 32) {
            const int koff = kt + quad * 8;
            const float4 xa = *(const float4*)&sPos[koff];
            const float4 xb = *(const float4*)&sPos[koff + 4];
            const float4 ya = *(const float4*)&sPos[PSTR + koff];
            const float4 yb = *(const float4*)&sPos[PSTR + koff + 4];
            const float4 za = *(const float4*)&sPos[2 * PSTR + koff];
            const float4 zb = *(const float4*)&sPos[2 * PSTR + koff + 4];

            short8 af;
            #define MK(PX,PY,PZ,IDX) { const float dx = prx-(PX), dy = pry-(PY), dz = prz-(PZ); \
                const float d2 = dx*dx + dy*dy + dz*dz; af[IDX] = (d2 < 6.25f) ? (short)0x3F80 : (short)0; }
            MK(xa.x, ya.x, za.x, 0) MK(xa.y, ya.y, za.y, 1) MK(xa.z, ya.z, za.z, 2) MK(xa.w, ya.w, za.w, 3)
            MK(xb.x, yb.x, zb.x, 4) MK(xb.y, yb.y, zb.y, 5) MK(xb.z, yb.z, zb.z, 6) MK(xb.w, yb.w, zb.w, 7)
            #undef MK

            const short8 b0 = *(const short8*)&sY[(ncol)      * YSTR + koff];
            const short8 b1 = *(const short8*)&sY[(16 + ncol) * YSTR + koff];
            const short8 b2 = *(const short8*)&sY[(32 + ncol) * YSTR + koff];
            const short8 b3 = *(const short8*)&sY[(48 + ncol) * YSTR + koff];

            acc0 = __builtin_amdgcn_mfma_f32_16x16x32_bf16(af, b0, acc0, 0, 0, 0);
            acc1 = __builtin_amdgcn_mfma_f32_16x16x32_bf16(af, b1, acc1, 0, 0, 0);
            acc2 = __builtin_amdgcn_mfma_f32_16x16x32_bf16(af, b2, acc2, 0, 0, 0);
            acc3 = __builtin_amdgcn_mfma_f32_16x16x32_bf16(af, b3, acc3, 0, 0, 0);
            accc = __builtin_amdgcn_mfma_f32_16x16x32_bf16(af, bones, accc, 0, 0, 0);
        }
    }

    // C layout: col = ncol, row = quad*4 + r  (verified m89/m91)
    const int orow0 = rowbase + wv * 16 + quad * 4;
    #pragma unroll
    for (int r = 0; r < 4; ++r) {
        const int orow = orow0 + r;
        atomicAdd(&y1s[(size_t)orow * 32 + ncol],      acc0[r] + acc2[r]);
        atomicAdd(&y1s[(size_t)orow * 32 + 16 + ncol], acc1[r] + acc3[r]);
        if (ncol == 0) atomicAdd(&cnt[orow], accc[r]);
    }
}

// ---------------- mlp2: h = relu(sum/(cnt+eps)); y2 = h@W2+b2 -> y2T hi/lo [16][N] ----------------
__global__ __launch_bounds__(256) void k_mlp2(
    const float* __restrict__ W2,    // (32,8)
    const float* __restrict__ b2,    // (8,)
    char* __restrict__ ws)
{
    __shared__ float sW2[256], sb2[8];
    __shared__ __hip_bfloat16 sT[16 * YSTR];
    const int tid = threadIdx.x;
    for (int i = tid; i < 256; i += THREADS) sW2[i] = W2[i];
    if (tid < 8) sb2[tid] = b2[tid];
    __syncthreads();

    const int row = blockIdx.x * THREADS + tid;
    const float* y1s = (const float*)(ws + Y1S_OFF);
    const float  cv  = ((const float*)(ws + CNT_OFF))[row];
    const float  inv = 1.0f / (cv + 1e-6f);

    float o[8];
    #pragma unroll
    for (int j = 0; j < 8; ++j) o[j] = sb2[j];
    const float4* s4 = (const float4*)(y1s + (size_t)row * 32);
    #pragma unroll
    for (int k = 0; k < 8; ++k) {
        const float4 v = s4[k];
        const float h0 = fmaxf(v.x * inv, 0.0f);
        const float h1 = fmaxf(v.y * inv, 0.0f);
        const float h2 = fmaxf(v.z * inv, 0.0f);
        const float h3 = fmaxf(v.w * inv, 0.0f);
        #pragma unroll
        for (int j = 0; j < 8; ++j)
            o[j] += h0 * sW2[(4*k+0)*8+j] + h1 * sW2[(4*k+1)*8+j]
                  + h2 * sW2[(4*k+2)*8+j] + h3 * sW2[(4*k+3)*8+j];
    }
    #pragma unroll
    for (int j = 0; j < 8; ++j) {
        const __hip_bfloat16 h = __float2bfloat16(o[j]);
        const __hip_bfloat16 l = __float2bfloat16(o[j] - bf2f(h));
        sT[j * YSTR + tid]       = h;
        sT[(8 + j) * YSTR + tid] = l;
    }
    __syncthreads();
    __hip_bfloat16* y2t = (__hip_bfloat16*)(ws + Y2T_OFF);
    const int kb = blockIdx.x * THREADS;
    const int c32 = tid & 31, r8 = tid >> 5;
    #pragma unroll
    for (int rr = 0; rr < 2; ++rr) {
        const int r = r8 + rr * 8;
        *(uint4*)(y2t + (size_t)r * N + kb + c32 * 8) = *(const uint4*)&sT[r * YSTR + c32 * 8];
    }
}

// ---------------- agg2: sums(A @ [y2_hi|y2_lo]) via MFMA (cnt reused) ----------------
__global__ __launch_bounds__(256) void k_agg2(char* __restrict__ ws)
{
    __shared__ __hip_bfloat16 sY[16 * YSTR];
    __shared__ float sPos[3 * PSTR];

    const float4* pos4 = (const float4*)(ws + POS4_OFF);
    const float* posT  = (const float*)(ws + POST_OFF);
    const __hip_bfloat16* y2t = (const __hip_bfloat16*)(ws + Y2T_OFF);
    float* y2s = (float*)(ws + Y2S_OFF);

    const int tid  = threadIdx.x;
    const int lane = tid & 63;
    const int wv   = tid >> 6;
    const int quad = lane >> 4;
    const int ncol = lane & 15;
    const int rowbase = blockIdx.x * 64;
    const int kcbase  = blockIdx.y * KCHUNK;

    const float4 pr = pos4[rowbase + wv * 16 + ncol];
    const float prx = pr.x, pry = pr.y, prz = pr.z;

    floatx4 acc = {0.f,0.f,0.f,0.f};

    const int c32 = tid & 31, r8 = tid >> 5;
    for (int kb = kcbase; kb < kcbase + KCHUNK; kb += BK) {
        __syncthreads();
        {
            #pragma unroll
            for (int rr = 0; rr < 2; ++rr) {
                const int r = r8 + rr * 8;
                *(uint4*)&sY[r * YSTR + c32 * 8] = *(const uint4*)(y2t + (size_t)r * N + kb + c32 * 8);
            }
            if (tid < 192) {
                const int dim = tid >> 6, i = tid & 63;
                *(float4*)&sPos[dim * PSTR + i * 4] = *(const float4*)(posT + (size_t)dim * N + kb + i * 4);
            }
        }
        __syncthreads();

        for (int kt = 0; kt < BK; kt += 32) {
            const int koff = kt + quad * 8;
            const float4 xa = *(const float4*)&sPos[koff];
            const float4 xb = *(const float4*)&sPos[koff + 4];
            const float4 ya = *(const float4*)&sPos[PSTR + koff];
            const float4 yb = *(const float4*)&sPos[PSTR + koff + 4];
            const float4 za = *(const float4*)&sPos[2 * PSTR + koff];
            const float4 zb = *(const float4*)&sPos[2 * PSTR + koff + 4];

            short8 af;
            #define MK(PX,PY,PZ,IDX) { const float dx = prx-(PX), dy = pry-(PY), dz = prz-(PZ); \
                const float d2 = dx*dx + dy*dy + dz*dz; af[IDX] = (d2 < 6.25f) ? (short)0x3F80 : (short)0; }
            MK(xa.x, ya.x, za.x, 0) MK(xa.y, ya.y, za.y, 1) MK(xa.z, ya.z, za.z, 2) MK(xa.w, ya.w, za.w, 3)
            MK(xb.x, yb.x, zb.x, 4) MK(xb.y, yb.y, zb.y, 5) MK(xb.z, yb.z, zb.z, 6) MK(xb.w, yb.w, zb.w, 7)
            #undef MK

            const short8 b0 = *(const short8*)&sY[ncol * YSTR + koff];
            acc = __builtin_amdgcn_mfma_f32_16x16x32_bf16(af, b0, acc, 0, 0, 0);
        }
    }

    // cols 0-7 = hi sums, 8-15 = lo sums -> combine via shfl_xor(8)
    const int orow0 = rowbase + wv * 16 + quad * 4;
    #pragma unroll
    for (int r = 0; r < 4; ++r) {
        const float partner = __shfl_xor(acc[r], 8);
        if (ncol < 8) {
            const int orow = orow0 + r;
            atomicAdd(&y2s[(size_t)orow * 8 + ncol], acc[r] + partner);
        }
    }
}

// ---------------- out = relu(sum/(cnt+eps)) -> float32 ----------------
__global__ __launch_bounds__(256) void k_out(char* __restrict__ ws, float* __restrict__ out)
{
    const int tid = threadIdx.x;
    const int row = blockIdx.x * THREADS + tid;
    const float* y2s = (const float*)(ws + Y2S_OFF);
    const float  cv  = ((const float*)(ws + CNT_OFF))[row];
    const float  inv = 1.0f / (cv + 1e-6f);
    const float* s = y2s + (size_t)row * 8;
    float4* op = (float4*)(out + (size_t)row * 8);
    op[0] = make_float4(fmaxf(s[0] * inv, 0.0f), fmaxf(s[1] * inv, 0.0f),
                        fmaxf(s[2] * inv, 0.0f), fmaxf(s[3] * inv, 0.0f));
    op[1] = make_float4(fmaxf(s[4] * inv, 0.0f), fmaxf(s[5] * inv, 0.0f),
                        fmaxf(s[6] * inv, 0.0f), fmaxf(s[7] * inv, 0.0f));
}

extern "C" void kernel_launch(void* const* d_in, const int* in_sizes, int n_in,
                              void* d_out, int out_size, void* d_ws, size_t ws_size,
                              hipStream_t stream) {
    (void)in_sizes; (void)n_in; (void)out_size; (void)ws_size;
    char* ws = (char*)d_ws;
    const float* lpf = (const float*)d_in[0];
    const float* B   = (const float*)d_in[1];
    const float* emb = (const float*)d_in[2];
    const float* W1  = (const float*)d_in[3];
    const float* b1  = (const float*)d_in[4];
    const float* W2  = (const float*)d_in[5];
    const float* b2  = (const float*)d_in[6];

    k_zero<<<64, THREADS, 0, stream>>>(ws);
    k_prep<<<N / THREADS, THREADS, 0, stream>>>(lpf, B, emb, W1, b1, ws);
    k_agg1<<<dim3(N / 64, KCHUNKS), THREADS, 0, stream>>>(ws);
    k_mlp2<<<N / THREADS, THREADS, 0, stream>>>(W2, b2, ws);
    k_agg2<<<dim3(N / 64, KCHUNKS), THREADS, 0, stream>>>(ws);
    k_out <<<N / THREADS, THREADS, 0, stream>>>(ws, (float*)d_out);
}